// Round 2
// baseline (174.389 us; speedup 1.0000x reference)
//
#include <hip/hip_runtime.h>
#include <hip/hip_bf16.h>

#define NTOK 2048
#define BATCH 4
#define EMB 256
#define NH 8
#define DHD 32
#define MROWS (NTOK*BATCH)      // 8192
#define NBE (MROWS*EMB)         // 2097152

typedef __attribute__((ext_vector_type(8))) __bf16 bf16x8;
typedef __attribute__((ext_vector_type(4))) float f32x4;
typedef __attribute__((ext_vector_type(8))) unsigned short ushort8;
typedef __attribute__((ext_vector_type(4))) unsigned int uint4v;

__device__ __forceinline__ float bf2f(unsigned short u){
  unsigned int v = ((unsigned int)u) << 16;
  return __builtin_bit_cast(float, v);
}
__device__ __forceinline__ unsigned short f2bf(float f){
  unsigned int u = __builtin_bit_cast(unsigned int, f);
  u += 0x7fffu + ((u >> 16) & 1u);
  return (unsigned short)(u >> 16);
}

// ---------------- K1: qin = bf16(x + query_pos), f32 in ----------------
__global__ __launch_bounds__(256) void k_add(const float* __restrict__ x,
                                             const float* __restrict__ qp,
                                             unsigned short* __restrict__ qin){
  int i = blockIdx.x * 256 + threadIdx.x;   // 8-elem chunks
  f32x4 a0 = ((const f32x4*)x)[2*i];
  f32x4 a1 = ((const f32x4*)x)[2*i+1];
  f32x4 b0 = ((const f32x4*)qp)[2*i];
  f32x4 b1 = ((const f32x4*)qp)[2*i+1];
  ushort8 o;
#pragma unroll
  for (int j = 0; j < 4; ++j){
    o[j]   = f2bf(a0[j] + b0[j]);
    o[j+4] = f2bf(a1[j] + b1[j]);
  }
  ((ushort8*)qin)[i] = o;
}

// ---------------- K2: transpose+cast 5 weights: wt[n][k] = bf16(W[k][n]) ----------------
__global__ __launch_bounds__(256) void k_transW(const float* __restrict__ s0,
                                                const float* __restrict__ s1,
                                                const float* __restrict__ s2,
                                                const float* __restrict__ s3,
                                                const float* __restrict__ s4,
                                                unsigned short* __restrict__ wt){
  const float* srcs[5] = {s0, s1, s2, s3, s4};
  int w = blockIdx.y;
  int k = blockIdx.x;
  int n = threadIdx.x;
  wt[w*65536 + n*256 + k] = f2bf(srcs[w][k*256 + n]);
}

// ---------------- K3: fused 4-way projection GEMM ----------------
__global__ __launch_bounds__(256) void k_proj(const unsigned short* __restrict__ qin,
                                              const unsigned short* __restrict__ wt,
                                              const float* __restrict__ bq,
                                              const float* __restrict__ bk,
                                              const float* __restrict__ br,
                                              const float* __restrict__ bs,
                                              const float* __restrict__ recv,
                                              const float* __restrict__ send,
                                              unsigned short* __restrict__ qbuf,
                                              unsigned short* __restrict__ kbuf,
                                              unsigned short* __restrict__ vsb,
                                              float* __restrict__ vrout,
                                              float* __restrict__ vsout){
  int m0 = blockIdx.x * 64;
  int gc = blockIdx.y * 64;
  int widx = gc >> 8;
  int c0 = gc & 255;
  int tid = threadIdx.x;
  int w = tid >> 6, lane = tid & 63;
  int lr = lane & 15, lg = lane >> 4;

  const unsigned short* wtp = wt + widx * 65536;
  const unsigned short* aptr = qin + (m0 + w*16 + lr) * 256 + lg * 8;

  f32x4 acc[4];
#pragma unroll
  for (int f = 0; f < 4; ++f) acc[f] = (f32x4){0.f, 0.f, 0.f, 0.f};

#pragma unroll
  for (int k0 = 0; k0 < 256; k0 += 32){
    bf16x8 af = *(const bf16x8*)(aptr + k0);
#pragma unroll
    for (int f = 0; f < 4; ++f){
      bf16x8 bfrag = *(const bf16x8*)(wtp + (c0 + f*16 + lr) * 256 + k0 + lg * 8);
      acc[f] = __builtin_amdgcn_mfma_f32_16x16x32_bf16(af, bfrag, acc[f], 0, 0, 0);
    }
  }

  const float* bias = (widx == 0) ? bq : (widx == 1) ? bk : (widx == 2) ? br : bs;
#pragma unroll
  for (int f = 0; f < 4; ++f){
#pragma unroll
    for (int i = 0; i < 4; ++i){
      int m = m0 + w*16 + lg*4 + i;
      int c = c0 + f*16 + lr;
      float v = acc[f][i] + bias[c];
      int idx = m * 256 + c;
      if (widx == 0)      qbuf[idx] = f2bf(v);
      else if (widx == 1) kbuf[idx] = f2bf(v);
      else if (widx == 2) vrout[idx] = v + recv[idx];
      else { float t = v + send[idx]; vsout[idx] = t; vsb[idx] = f2bf(t); }
    }
  }
}

// ---------------- K4: flash attention + vr add -> ctx (bf16) ----------------
__global__ __launch_bounds__(256) void k_attn(const unsigned short* __restrict__ qbuf,
                                              const unsigned short* __restrict__ kbuf,
                                              const unsigned short* __restrict__ vsb,
                                              const float* __restrict__ vrbuf,
                                              unsigned short* __restrict__ ctx){
  int qt0 = blockIdx.x * 64;
  int b = blockIdx.y;
  int h = blockIdx.z;
  int tid = threadIdx.x;
  int w = tid >> 6, lane = tid & 63;
  int lr = lane & 15, lg = lane >> 4;

  __shared__ unsigned short Kt[2048];        // [64 kv][32 d], XOR-swizzled
  __shared__ unsigned short Vt[2048];        // [32 d][64 kv], transposed, XOR-swizzled
  __shared__ unsigned short Pl[4][1024];     // per-wave [16 q][64 kv], XOR-swizzled

  char* KtB = (char*)Kt;
  char* VtB = (char*)Vt;
  char* PB  = (char*)&Pl[w][0];

  bf16x8 qf = *(const bf16x8*)(qbuf + ((qt0 + w*16 + lr) * BATCH + b) * EMB + h * DHD + lg * 8);

  f32x4 accO0 = (f32x4){0.f,0.f,0.f,0.f};
  f32x4 accO1 = (f32x4){0.f,0.f,0.f,0.f};
  float mrun[4] = {-INFINITY, -INFINITY, -INFINITY, -INFINITY};
  float lsum[4] = {0.f, 0.f, 0.f, 0.f};
  const float scale = 0.17677669529663687f;  // 1/sqrt(32)

  for (int kv0 = 0; kv0 < NTOK; kv0 += 64){
    __syncthreads();
    {
      int row = tid >> 2;                 // kv row 0..63
      int cc  = (tid & 3) * 8;            // d chunk
      int gidx = ((kv0 + row) * BATCH + b) * EMB + h * DHD + cc;
      uint4v kval = *(const uint4v*)(kbuf + gidx);
      int kb = (row*64 + cc*2) ^ ((row & 7) << 4);
      *(uint4v*)(KtB + kb) = kval;
      ushort8 vval = *(const ushort8*)(vsb + gidx);
#pragma unroll
      for (int i = 0; i < 8; ++i){
        int d = cc + i;
        int vb = (d*128 + row*2) ^ ((d & 7) << 4);
        *(unsigned short*)(VtB + vb) = vval[i];
      }
    }
    __syncthreads();

    // S = Q K^T  (4 kv-subtiles of 16)
    f32x4 s[4];
#pragma unroll
    for (int j = 0; j < 4; ++j){
      int row = j*16 + lr;
      int kb = (row*64 + lg*16) ^ ((row & 7) << 4);
      bf16x8 kf = *(const bf16x8*)(KtB + kb);
      f32x4 z = (f32x4){0.f,0.f,0.f,0.f};
      s[j] = __builtin_amdgcn_mfma_f32_16x16x32_bf16(qf, kf, z, 0, 0, 0);
#pragma unroll
      for (int i = 0; i < 4; ++i) s[j][i] *= scale;
    }

    // online softmax stats (reduce across 16 lanes = kv cols)
#pragma unroll
    for (int i = 0; i < 4; ++i){
      float mx = fmaxf(fmaxf(s[0][i], s[1][i]), fmaxf(s[2][i], s[3][i]));
#pragma unroll
      for (int d = 1; d < 16; d <<= 1) mx = fmaxf(mx, __shfl_xor(mx, d, 16));
      float mnew = fmaxf(mrun[i], mx);
      float corr = __expf(mrun[i] - mnew);
      mrun[i] = mnew;
      accO0[i] *= corr;
      accO1[i] *= corr;
      lsum[i] *= corr;
    }

    // P = exp(S - m) -> per-wave LDS (swizzled) + row sums
    float ps[4] = {0.f, 0.f, 0.f, 0.f};
#pragma unroll
    for (int j = 0; j < 4; ++j){
#pragma unroll
      for (int i = 0; i < 4; ++i){
        float p = __expf(s[j][i] - mrun[i]);
        ps[i] += p;
        int q = lg*4 + i;
        int pb = (q*128 + (j*16 + lr)*2) ^ ((q & 7) << 4);
        *(unsigned short*)(PB + pb) = f2bf(p);
      }
    }
#pragma unroll
    for (int i = 0; i < 4; ++i){
      float t = ps[i];
#pragma unroll
      for (int d = 1; d < 16; d <<= 1) t += __shfl_xor(t, d, 16);
      lsum[i] += t;
    }

    // PV: 2 kv-chunks of 32, 2 d-halves of 16
#pragma unroll
    for (int c = 0; c < 2; ++c){
      int pb = (lr*128 + c*64 + lg*16) ^ ((lr & 7) << 4);
      bf16x8 pf = *(const bf16x8*)(PB + pb);
      int d0 = lr;
      int vb0 = (d0*128 + c*64 + lg*16) ^ ((d0 & 7) << 4);
      bf16x8 vf0 = *(const bf16x8*)(VtB + vb0);
      accO0 = __builtin_amdgcn_mfma_f32_16x16x32_bf16(pf, vf0, accO0, 0, 0, 0);
      int d1 = 16 + lr;
      int vb1 = (d1*128 + c*64 + lg*16) ^ ((d1 & 7) << 4);
      bf16x8 vf1 = *(const bf16x8*)(VtB + vb1);
      accO1 = __builtin_amdgcn_mfma_f32_16x16x32_bf16(pf, vf1, accO1, 0, 0, 0);
    }
  }

  // epilogue: normalize, add vr (f32), write ctx as bf16
#pragma unroll
  for (int i = 0; i < 4; ++i){
    float inv = 1.0f / lsum[i];
    int q = qt0 + w*16 + lg*4 + i;
    int mrow = q * BATCH + b;
    int e0 = h * DHD + lr;
    int idx = mrow * EMB + e0;
    ctx[idx]      = f2bf(accO0[i] * inv + vrbuf[idx]);
    ctx[idx + 16] = f2bf(accO1[i] * inv + vrbuf[idx + 16]);
  }
}

// ---------------- K5: out = x + ctx @ Wo + bo  (f32 out) ----------------
__global__ __launch_bounds__(256) void k_out(const unsigned short* __restrict__ ctx,
                                             const unsigned short* __restrict__ wto,
                                             const float* __restrict__ bo,
                                             const float* __restrict__ x,
                                             float* __restrict__ out0){
  int m0 = blockIdx.x * 64;
  int c0 = blockIdx.y * 64;
  int tid = threadIdx.x;
  int w = tid >> 6, lane = tid & 63;
  int lr = lane & 15, lg = lane >> 4;

  const unsigned short* aptr = ctx + (m0 + w*16 + lr) * 256 + lg * 8;

  f32x4 acc[4];
#pragma unroll
  for (int f = 0; f < 4; ++f) acc[f] = (f32x4){0.f, 0.f, 0.f, 0.f};

#pragma unroll
  for (int k0 = 0; k0 < 256; k0 += 32){
    bf16x8 af = *(const bf16x8*)(aptr + k0);
#pragma unroll
    for (int f = 0; f < 4; ++f){
      bf16x8 bfrag = *(const bf16x8*)(wto + (c0 + f*16 + lr) * 256 + k0 + lg * 8);
      acc[f] = __builtin_amdgcn_mfma_f32_16x16x32_bf16(af, bfrag, acc[f], 0, 0, 0);
    }
  }

#pragma unroll
  for (int f = 0; f < 4; ++f){
#pragma unroll
    for (int i = 0; i < 4; ++i){
      int m = m0 + w*16 + lg*4 + i;
      int c = c0 + f*16 + lr;
      int idx = m * 256 + c;
      out0[idx] = acc[f][i] + bo[c] + x[idx];
    }
  }
}

extern "C" void kernel_launch(void* const* d_in, const int* in_sizes, int n_in,
                              void* d_out, int out_size, void* d_ws, size_t ws_size,
                              hipStream_t stream){
  const float* x    = (const float*)d_in[0];
  const float* qp   = (const float*)d_in[1];
  const float* recv = (const float*)d_in[2];
  const float* send = (const float*)d_in[3];
  const float* Wq   = (const float*)d_in[4];
  const float* bq   = (const float*)d_in[5];
  const float* Wk   = (const float*)d_in[6];
  const float* bk   = (const float*)d_in[7];
  const float* Wr   = (const float*)d_in[8];
  const float* br   = (const float*)d_in[9];
  const float* Wsv  = (const float*)d_in[10];
  const float* bsv  = (const float*)d_in[11];
  const float* Wo   = (const float*)d_in[12];
  const float* bo   = (const float*)d_in[13];

  float* out0  = (float*)d_out;
  float* vrout = out0 + NBE;
  float* vsout = out0 + 2*NBE;

  unsigned short* ws   = (unsigned short*)d_ws;
  unsigned short* qin  = ws;                 // reused as ctx after proj
  unsigned short* qbuf = ws + NBE;
  unsigned short* kbuf = ws + 2*NBE;
  unsigned short* vsb  = ws + 3*NBE;
  unsigned short* wt   = ws + 4*NBE;         // 5 * 65536

  hipLaunchKernelGGL(k_add, dim3(NBE/8/256), dim3(256), 0, stream, x, qp, qin);
  hipLaunchKernelGGL(k_transW, dim3(256, 5), dim3(256), 0, stream, Wq, Wk, Wr, Wsv, Wo, wt);
  hipLaunchKernelGGL(k_proj, dim3(128, 16), dim3(256), 0, stream,
                     qin, wt, bq, bk, br, bsv, recv, send, qbuf, kbuf, vsb, vrout, vsout);
  hipLaunchKernelGGL(k_attn, dim3(32, 4, 8), dim3(256), 0, stream,
                     qbuf, kbuf, vsb, vrout, qin /*ctx*/);
  hipLaunchKernelGGL(k_out, dim3(128, 4), dim3(256), 0, stream,
                     qin /*ctx*/, wt + 4*65536, bo, x, out0);
}